// Round 4
// baseline (638.210 us; speedup 1.0000x reference)
//
#include <hip/hip_runtime.h>

#define NTH  1024
#define XLEN 368
#define NF   112

typedef short bh8 __attribute__((ext_vector_type(8)));
typedef float fv4 __attribute__((ext_vector_type(4)));

// ---- LDS layout (ushort-element offsets) ----
#define IMG_OFF 0            // 114x114 bf16 zero-halo img
#define IMG_LD  114
#define X0H 12996            // xsp bf16 hi, even-pair copy   (1024 el)
#define X1H 14020            // xsp bf16 hi, shifted-by-1     (1024 el)
#define X0L 15044            // xsp bf16 lo residual          (1024 el)
#define X1L 16068            // xsp bf16 lo residual shifted  (1024 el)
#define H1_OFF 17092         // 6 x 58 x 58 bf16 zero-halo    (20184 el)
#define TOT_E 37276          // *2 = 74552 bytes  -> 2 blocks/CU

// time-aliased late regions (img/xsp dead)
#define H2_OFF 0             // 12 x 30 x 30 bf16  [0,10800)
#define H3_OFF 10800         // 12 x 16 x 16 bf16  [10800,13872)
// float-view offsets (h2 dead by then)
#define H4_F 0               // 588 f32 (12x7x7 flatten)
#define FC1_F 600            // 48 f32
#define LG_F 652             // 4 f32

__device__ __forceinline__ unsigned short bfbits(float v) {
  union { __bf16 b; unsigned short u; } c;
  c.b = (__bf16)v;
  return c.u;
}
__device__ __forceinline__ float f_lo(unsigned u) {
  return __uint_as_float(u << 16);
}
__device__ __forceinline__ float f_hi(unsigned u) {
  return __uint_as_float(u & 0xffff0000u);
}

// A-fragments (hi at [idx], lo residual at [idx + total]) in MFMA order.
__global__ void prep_A(const float* __restrict__ ww, int K, int nks,
                       bh8* __restrict__ Aarr) {
  int idx = blockIdx.x * 256 + threadIdx.x;
  int total = 7 * nks * 64;
  if (idx >= total) return;
  int lane = idx & 63;
  int fk = idx >> 6;
  int ks = fk % nks, ft = fk / nks;
  int frow = ft * 16 + (lane & 15);
  int k0 = ks * 32 + 8 * (lane >> 4);
  union { bh8 s; unsigned short h[8]; } oh, ol;
  #pragma unroll
  for (int e = 0; e < 8; ++e) {
    int k = k0 + e;
    float v = (k < K) ? ww[(size_t)frow * K + k] : 0.f;
    unsigned short hb = bfbits(v);
    oh.h[e] = hb;
    ol.h[e] = bfbits(v - __uint_as_float((unsigned)hb << 16));
  }
  Aarr[idx] = oh.s;
  Aarr[idx + total] = ol.s;
}

__device__ __forceinline__ void conv4acc(const float (&p)[4][4],
                                         const float (&w9)[9],
                                         float (&acc)[4]) {
  #pragma unroll
  for (int dy = 0; dy < 2; ++dy)
    #pragma unroll
    for (int dx = 0; dx < 2; ++dx) {
      float a = 0.f;
      #pragma unroll
      for (int dr = 0; dr < 3; ++dr)
        #pragma unroll
        for (int dc = 0; dc < 3; ++dc)
          a = fmaf(p[dy + dr][dx + dc], w9[dr * 3 + dc], a);
      acc[dy * 2 + dx] += a;
    }
}

__device__ __forceinline__ void load_patch(const unsigned short* su, int baseEl,
                                           int ldEl, float (&p)[4][4]) {
  #pragma unroll
  for (int i = 0; i < 4; ++i) {
    unsigned a = *(const unsigned*)(su + baseEl + i * ldEl);
    unsigned b = *(const unsigned*)(su + baseEl + i * ldEl + 2);
    p[i][0] = f_lo(a); p[i][1] = f_hi(a);
    p[i][2] = f_lo(b); p[i][3] = f_hi(b);
  }
}

template <bool PRE>
__global__ __launch_bounds__(NTH, 8) void fused_convnet(
    const float* __restrict__ x, const float* __restrict__ ww,
    const bh8* __restrict__ Aarr, int K, int nks,
    const float* __restrict__ c1w, const float* __restrict__ c1b,
    const float* __restrict__ c2w, const float* __restrict__ c2b,
    const float* __restrict__ c3w, const float* __restrict__ c3b,
    const float* __restrict__ c4w, const float* __restrict__ c4b,
    const float* __restrict__ f1w, const float* __restrict__ f1b,
    const float* __restrict__ f2w, const float* __restrict__ f2b,
    float* __restrict__ out) {
  extern __shared__ unsigned short su[];
  float* sfl = (float*)su;
  const int b = blockIdx.x;
  const int tid = threadIdx.x;
  const int pad = (K - 1) >> 1;

  // ---- phase 0: halo rings + stage xsp (hi/lo, dual parity) ----
  for (int m = tid; m < 452; m += NTH) {  // img ring
    int r, c;
    if (m < 114) { r = 0; c = m; }
    else if (m < 228) { r = 113; c = m - 114; }
    else if (m < 340) { r = m - 228 + 1; c = 0; }
    else { r = m - 340 + 1; c = 113; }
    su[IMG_OFF + r * IMG_LD + c] = 0;
  }
  for (int m = tid; m < 1368; m += NTH) {  // h1 rings
    int ch = m / 228, w = m - ch * 228, r, c;
    if (w < 58) { r = 0; c = w; }
    else if (w < 116) { r = 57; c = w - 58; }
    else if (w < 172) { r = w - 116 + 1; c = 0; }
    else { r = w - 172 + 1; c = 57; }
    su[H1_OFF + ch * 3364 + r * 58 + c] = 0;
  }
  for (int i = tid; i < 1024; i += NTH) {
    float f0 = 0.f, f1 = 0.f;
    int xi = i - pad;
    if (xi >= 0 && xi < XLEN) f0 = x[(size_t)b * XLEN + xi];
    if (xi + 1 >= 0 && xi + 1 < XLEN) f1 = x[(size_t)b * XLEN + xi + 1];
    unsigned short h0 = bfbits(f0), h1v = bfbits(f1);
    su[X0H + i] = h0;
    su[X1H + i] = h1v;
    su[X0L + i] = bfbits(f0 - __uint_as_float((unsigned)h0 << 16));
    su[X1L + i] = bfbits(f1 - __uint_as_float((unsigned)h1v << 16));
  }
  __syncthreads();

  // ---- phase 1: CWT via hi/lo-split bf16 MFMA -> img bf16 ----
  {
    const int wid = tid >> 6, lane = tid & 63;
    if (wid < 14) {
      const int jt = wid % 7, fg = wid / 7;
      const int ft0 = fg * 4;
      const int nft = fg ? 3 : 4;
      const int jcol = jt * 16 + (lane & 15);
      const int selj = (jcol == NF - 1)
          ? (XLEN - 1)
          : (int)((double)jcol * ((double)(XLEN - 1) / (double)(NF - 1)));
      const int koff = (lane >> 4) * 8;
      const int atot = 7 * nks * 64;
      fv4 acc[4];
      #pragma unroll
      for (int t = 0; t < 4; ++t)
        #pragma unroll
        for (int r = 0; r < 4; ++r) acc[t][r] = 0.f;
      for (int ks = 0; ks < nks; ++ks) {
        const int kbase = selj + (ks << 5) + koff;
        const int par = kbase & 1;
        const int e0 = kbase - par;
        const unsigned* ph = (const unsigned*)(su + (par ? X1H : X0H) + e0);
        const unsigned* pl = (const unsigned*)(su + (par ? X1L : X0L) + e0);
        union { bh8 v; unsigned u[4]; } bh_, bl_;
        #pragma unroll
        for (int j = 0; j < 4; ++j) { bh_.u[j] = ph[j]; bl_.u[j] = pl[j]; }
        #pragma unroll
        for (int t = 0; t < 4; ++t)
          if (t < nft) {
            bh8 ah, al;
            if (PRE) {
              int ai = ((ft0 + t) * nks + ks) * 64 + lane;
              ah = Aarr[ai];
              al = Aarr[ai + atot];
            } else {
              const int frow = (ft0 + t) * 16 + (lane & 15);
              union { bh8 s; unsigned short h[8]; } ha, la;
              #pragma unroll
              for (int e = 0; e < 8; ++e) {
                int k = (ks << 5) + koff + e;
                float v = (k < K) ? ww[(size_t)frow * K + k] : 0.f;
                unsigned short hb = bfbits(v);
                ha.h[e] = hb;
                la.h[e] = bfbits(v - __uint_as_float((unsigned)hb << 16));
              }
              ah = ha.s; al = la.s;
            }
            acc[t] = __builtin_amdgcn_mfma_f32_16x16x32_bf16(ah, bh_.v,
                                                             acc[t], 0, 0, 0);
            acc[t] = __builtin_amdgcn_mfma_f32_16x16x32_bf16(al, bh_.v,
                                                             acc[t], 0, 0, 0);
            acc[t] = __builtin_amdgcn_mfma_f32_16x16x32_bf16(ah, bl_.v,
                                                             acc[t], 0, 0, 0);
          }
      }
      const int col = jt * 16 + (lane & 15) + 1;
      #pragma unroll
      for (int t = 0; t < 4; ++t)
        if (t < nft) {
          const int fbase = (ft0 + t) * 16 + (lane >> 4) * 4 + 1;
          #pragma unroll
          for (int r = 0; r < 4; ++r)
            su[IMG_OFF + (fbase + r) * IMG_LD + col] = bfbits(acc[t][r]);
        }
    }
  }
  __syncthreads();

  // ---- phase 2: conv1(1->6)+relu+pool -> h1 bf16 ----
  for (int it = tid; it < 3136; it += NTH) {
    int pr = it / 56, pc = it - pr * 56;
    float p[4][4];
    load_patch(su, IMG_OFF + (pr * 2) * IMG_LD + pc * 2, IMG_LD, p);
    #pragma unroll
    for (int oc = 0; oc < 6; ++oc) {
      float w9[9];
      #pragma unroll
      for (int t = 0; t < 9; ++t) w9[t] = c1w[oc * 9 + t];
      float acc[4] = {c1b[oc], c1b[oc], c1b[oc], c1b[oc]};
      conv4acc(p, w9, acc);
      float m = fmaxf(fmaxf(acc[0], acc[1]), fmaxf(acc[2], acc[3]));
      su[H1_OFF + oc * 3364 + (pr + 1) * 58 + (pc + 1)] = bfbits(fmaxf(m, 0.f));
    }
  }
  __syncthreads();

  // ---- phase 3+4: conv2 (tid<784) | h2/h3 rings (tid>=784) ----
  if (tid < 784) {
    int pr = tid / 28, pc = tid - pr * 28;
    #pragma unroll
    for (int ob = 0; ob < 2; ++ob) {
      int oc0 = ob * 6;
      float acc[6][4];
      #pragma unroll
      for (int q = 0; q < 6; ++q) {
        float bia = c2b[oc0 + q];
        #pragma unroll
        for (int t = 0; t < 4; ++t) acc[q][t] = bia;
      }
      for (int ic = 0; ic < 6; ++ic) {
        float p[4][4];
        load_patch(su, H1_OFF + ic * 3364 + (pr * 2) * 58 + pc * 2, 58, p);
        #pragma unroll
        for (int q = 0; q < 6; ++q) {
          const float* wp = c2w + ((size_t)(oc0 + q) * 6 + ic) * 9;
          float w9[9];
          #pragma unroll
          for (int t = 0; t < 9; ++t) w9[t] = wp[t];
          conv4acc(p, w9, acc[q]);
        }
      }
      #pragma unroll
      for (int q = 0; q < 6; ++q) {
        float m = fmaxf(fmaxf(acc[q][0], acc[q][1]),
                        fmaxf(acc[q][2], acc[q][3]));
        su[H2_OFF + (oc0 + q) * 900 + (pr + 1) * 30 + (pc + 1)] =
            bfbits(fmaxf(m, 0.f));
      }
    }
  } else {
    for (int m = tid - 784; m < 1392; m += 240) {  // h2 rings
      int ch = m / 116, w = m - ch * 116, r, c;
      if (w < 30) { r = 0; c = w; }
      else if (w < 60) { r = 29; c = w - 30; }
      else if (w < 88) { r = w - 60 + 1; c = 0; }
      else { r = w - 88 + 1; c = 29; }
      su[H2_OFF + ch * 900 + r * 30 + c] = 0;
    }
    for (int m = tid - 784; m < 720; m += 240) {  // h3 rings
      int ch = m / 60, w = m - ch * 60, r, c;
      if (w < 16) { r = 0; c = w; }
      else if (w < 32) { r = 15; c = w - 16; }
      else if (w < 46) { r = w - 32 + 1; c = 0; }
      else { r = w - 46 + 1; c = 15; }
      su[H3_OFF + ch * 256 + r * 16 + c] = 0;
    }
  }
  __syncthreads();

  // ---- phase 5: conv3(12->12)+relu+pool quads -> h3 bf16 ----
  if (tid < 784) {
    int pos = tid >> 2, ocq = tid & 3;
    int pr = pos / 14, pc = pos - pr * 14;
    int oc0 = ocq * 3;
    float acc[3][4];
    #pragma unroll
    for (int q = 0; q < 3; ++q) {
      float bia = c3b[oc0 + q];
      #pragma unroll
      for (int t = 0; t < 4; ++t) acc[q][t] = bia;
    }
    for (int ic = 0; ic < 12; ++ic) {
      float p[4][4];
      load_patch(su, H2_OFF + ic * 900 + (pr * 2) * 30 + pc * 2, 30, p);
      #pragma unroll
      for (int q = 0; q < 3; ++q) {
        const float* wp = c3w + ((size_t)(oc0 + q) * 12 + ic) * 9;
        float w9[9];
        #pragma unroll
        for (int t = 0; t < 9; ++t) w9[t] = wp[t];
        conv4acc(p, w9, acc[q]);
      }
    }
    #pragma unroll
    for (int q = 0; q < 3; ++q) {
      float m = fmaxf(fmaxf(acc[q][0], acc[q][1]), fmaxf(acc[q][2], acc[q][3]));
      su[H3_OFF + (oc0 + q) * 256 + (pr + 1) * 16 + (pc + 1)] =
          bfbits(fmaxf(m, 0.f));
    }
  }
  __syncthreads();

  // ---- phase 6: conv4(12->12)+relu+pool quads -> h4 f32 flat ----
  if (tid < 196) {
    int pos = tid >> 2, ocq = tid & 3;
    int pr = pos / 7, pc = pos - pr * 7;
    int oc0 = ocq * 3;
    float acc[3][4];
    #pragma unroll
    for (int q = 0; q < 3; ++q) {
      float bia = c4b[oc0 + q];
      #pragma unroll
      for (int t = 0; t < 4; ++t) acc[q][t] = bia;
    }
    for (int ic = 0; ic < 12; ++ic) {
      float p[4][4];
      load_patch(su, H3_OFF + ic * 256 + (pr * 2) * 16 + pc * 2, 16, p);
      #pragma unroll
      for (int q = 0; q < 3; ++q) {
        const float* wp = c4w + ((size_t)(oc0 + q) * 12 + ic) * 9;
        float w9[9];
        #pragma unroll
        for (int t = 0; t < 9; ++t) w9[t] = wp[t];
        conv4acc(p, w9, acc[q]);
      }
    }
    #pragma unroll
    for (int q = 0; q < 3; ++q) {
      float m = fmaxf(fmaxf(acc[q][0], acc[q][1]), fmaxf(acc[q][2], acc[q][3]));
      sfl[H4_F + (oc0 + q) * 49 + pr * 7 + pc] = fmaxf(m, 0.f);
    }
  }
  __syncthreads();

  // ---- phase 7: fc1 (588 -> 48), one wave per output ----
  {
    int wv = tid >> 6, ln = tid & 63;
    for (int o = wv; o < 48; o += 16) {
      float s = 0.f;
      for (int i = ln; i < 588; i += 64)
        s += sfl[H4_F + i] * f1w[(size_t)o * 588 + i];
      #pragma unroll
      for (int off = 32; off > 0; off >>= 1) s += __shfl_down(s, off);
      if (ln == 0) sfl[FC1_F + o] = fmaxf(s + f1b[o], 0.f);
    }
  }
  __syncthreads();

  // ---- phase 8: fc2 (48 -> 4) + softmax ----
  if (tid < 4) {
    float s = f2b[tid];
    for (int i = 0; i < 48; ++i) s += sfl[FC1_F + i] * f2w[tid * 48 + i];
    sfl[LG_F + tid] = s;
  }
  __syncthreads();
  if (tid < 4) {
    float l0 = sfl[LG_F + 0], l1 = sfl[LG_F + 1];
    float l2 = sfl[LG_F + 2], l3 = sfl[LG_F + 3];
    float m = fmaxf(fmaxf(l0, l1), fmaxf(l2, l3));
    float e0 = expf(l0 - m), e1 = expf(l1 - m);
    float e2 = expf(l2 - m), e3 = expf(l3 - m);
    float ssum = e0 + e1 + e2 + e3;
    out[(size_t)b * 4 + tid] = expf(sfl[LG_F + tid] - m) / ssum;
  }
}

extern "C" void kernel_launch(void* const* d_in, const int* in_sizes, int n_in,
                              void* d_out, int out_size, void* d_ws,
                              size_t ws_size, hipStream_t stream) {
  const float* x   = (const float*)d_in[0];
  const float* ww  = (const float*)d_in[1];
  const float* c1w = (const float*)d_in[2];
  const float* c1b = (const float*)d_in[3];
  const float* c2w = (const float*)d_in[4];
  const float* c2b = (const float*)d_in[5];
  const float* c3w = (const float*)d_in[6];
  const float* c3b = (const float*)d_in[7];
  const float* c4w = (const float*)d_in[8];
  const float* c4b = (const float*)d_in[9];
  const float* f1w = (const float*)d_in[10];
  const float* f1b = (const float*)d_in[11];
  const float* f2w = (const float*)d_in[12];
  const float* f2b = (const float*)d_in[13];
  float* out = (float*)d_out;

  const int B = in_sizes[0] / XLEN;
  const int K = in_sizes[1] / NF;  // 561
  const int nks = (K + 31) / 32;   // 18

  const size_t abytes = (size_t)2 * 7 * nks * 64 * sizeof(bh8);
  const bool pre = ws_size >= abytes;
  bh8* Aarr = (bh8*)d_ws;

  const size_t smem = (size_t)TOT_E * sizeof(unsigned short);  // 74552 B

  if (pre) {
    int items = 7 * nks * 64;
    hipLaunchKernelGGL(prep_A, dim3((items + 255) / 256), dim3(256), 0, stream,
                       ww, K, nks, Aarr);
    hipFuncSetAttribute((const void*)fused_convnet<true>,
                        hipFuncAttributeMaxDynamicSharedMemorySize, (int)smem);
    hipLaunchKernelGGL(fused_convnet<true>, dim3(B), dim3(NTH), smem, stream,
                       x, ww, Aarr, K, nks, c1w, c1b, c2w, c2b, c3w, c3b,
                       c4w, c4b, f1w, f1b, f2w, f2b, out);
  } else {
    hipFuncSetAttribute((const void*)fused_convnet<false>,
                        hipFuncAttributeMaxDynamicSharedMemorySize, (int)smem);
    hipLaunchKernelGGL(fused_convnet<false>, dim3(B), dim3(NTH), smem, stream,
                       x, ww, Aarr, K, nks, c1w, c1b, c2w, c2b, c3w, c3b,
                       c4w, c4b, f1w, f1b, f2w, f2b, out);
  }
}